// Round 4
// baseline (906.961 us; speedup 1.0000x reference)
//
#include <hip/hip_runtime.h>
#include <stdint.h>

typedef unsigned short u16;
typedef __bf16 bf16x8 __attribute__((ext_vector_type(8)));
typedef unsigned short u16x8 __attribute__((ext_vector_type(8)));
typedef unsigned short u16x4 __attribute__((ext_vector_type(4)));
typedef float f32x4 __attribute__((ext_vector_type(4)));

#define B_ 2
#define S_ 2048
#define HID_ 4096
#define NH_ 32
#define NKV_ 8
#define HD_ 128
#define NTOT_ 6144  // NH*HD + 2*NKV*HD
#define SCALE_ 0.08838834764831845f

// async global->LDS, 16B per lane, wave-uniform LDS base + lane*16 linear dest
#define GLD16(gp, lp)                                                     \
  __builtin_amdgcn_global_load_lds(                                       \
      (__attribute__((address_space(1))) void*)(gp),                      \
      (__attribute__((address_space(3))) void*)(lp), 16, 0, 0)

// ---------- bf16 helpers ----------
__device__ __forceinline__ u16 f2b(float f) {
  union { float f; uint32_t u; } v; v.f = f;
  uint32_t u = v.u;
  u = u + 0x7fffu + ((u >> 16) & 1u);   // round-to-nearest-even
  return (u16)(u >> 16);
}
__device__ __forceinline__ float b2f(u16 s) {
  union { uint32_t u; float f; } v; v.u = ((uint32_t)s) << 16;
  return v.f;
}
__device__ __forceinline__ bf16x8 ldb8(const u16* p) {
  u16x8 u = *(const u16x8*)p;
  return __builtin_bit_cast(bf16x8, u);
}
__device__ __forceinline__ bf16x8 ldb8b(const char* p) {
  u16x8 u = *(const u16x8*)p;
  return __builtin_bit_cast(bf16x8, u);
}

// ---------- kernel 1: f32 -> bf16 (vectorized) ----------
__global__ __launch_bounds__(256) void k_convx(const float* __restrict__ src,
                                               u16* __restrict__ dst, int n4) {
  int i = blockIdx.x * 256 + threadIdx.x;
  if (i >= n4) return;
  const float4 v = ((const float4*)src)[i];
  u16x4 o = { f2b(v.x), f2b(v.y), f2b(v.z), f2b(v.w) };
  *(u16x4*)(dst + (size_t)i * 4) = o;
}

// ---------- kernel 2: transpose-convert W f32 [Kd][N] -> bf16 [N][Kd] ----------
__global__ __launch_bounds__(256) void k_convT(const float* __restrict__ src,
                                               u16* __restrict__ dst, int N, int Kd) {
  __shared__ u16 tile[64][65];
  int k0 = blockIdx.x * 64, n0 = blockIdx.y * 64;
  int t = threadIdx.x;
  int rr = t >> 4;          // 0..15
  int cc = (t & 15) * 4;    // 0..60
#pragma unroll
  for (int p = 0; p < 4; ++p) {
    int r = p * 16 + rr;
    float4 v = *(const float4*)&src[(size_t)(k0 + r) * N + n0 + cc];
    tile[cc + 0][r] = f2b(v.x);
    tile[cc + 1][r] = f2b(v.y);
    tile[cc + 2][r] = f2b(v.z);
    tile[cc + 3][r] = f2b(v.w);
  }
  __syncthreads();
#pragma unroll
  for (int p = 0; p < 4; ++p) {
    int n = p * 16 + rr;
    u16x4 o = { tile[n][cc], tile[n][cc + 1], tile[n][cc + 2], tile[n][cc + 3] };
    *(u16x4*)&dst[(size_t)(n0 + n) * Kd + k0 + cc] = o;
  }
}

// ---------- kernel 3: bf16 GEMM, 128x128 tile, 4 waves, 16x16x32 MFMA ----------
// global_load_lds width-16 staging with FRAGMENT-MAJOR LDS layout:
//   16B chunk at byte g*1024 + c*256 + r*16 holds T[g*16+r][c*8 .. c*8+7]
// so every MFMA fragment ds_read_b128 is base + g*1024 + lane*16 (contiguous
// 1024B per wave -> zero bank conflicts, wave-uniform addressing).
// A: [M][Kd] bf16 row-major. Bt: [N][Kd] bf16 (B transposed).
// MODE 0: QKV epilogue (scatter to Q[b,h,s,d], K[b,kv,s,d], V^T[b,kv,d,s], bf16)
// MODE 1: f32 C output [M][N]
template <int MODE>
__global__ __launch_bounds__(256) void k_gemm(const u16* __restrict__ A,
                                              const u16* __restrict__ Bt,
                                              float* __restrict__ Cf,
                                              u16* __restrict__ Qb,
                                              u16* __restrict__ Kb,
                                              u16* __restrict__ Vb,
                                              int M, int N, int Kd) {
  __shared__ __align__(16) u16 As[4096];   // 8KB, fragment-major
  __shared__ __align__(16) u16 Bs[4096];   // 8KB, fragment-major
  int m0 = blockIdx.y * 128, n0 = blockIdx.x * 128;
  int t = threadIdx.x, lane = t & 63, wave = t >> 6;
  int wr = wave >> 1, wc = wave & 1;
  int lg = lane >> 4, l16 = lane & 15;
  f32x4 acc[4][4] = {};

  // staging sources: instruction for group g covers rows g*16+(lane&15),
  // k-chunk (lane>>4). Wave stages groups {wave, wave+4} of both tiles.
  const u16* pA1 = A  + (size_t)(m0 + wave * 16 + l16) * Kd + lg * 8;
  const u16* pA2 = pA1 + (size_t)64 * Kd;
  const u16* pB1 = Bt + (size_t)(n0 + wave * 16 + l16) * Kd + lg * 8;
  const u16* pB2 = pB1 + (size_t)64 * Kd;
  u16* dA1 = As + wave * 512;        // g = wave
  u16* dA2 = As + (wave + 4) * 512;  // g = wave+4
  u16* dB1 = Bs + wave * 512;
  u16* dB2 = Bs + (wave + 4) * 512;

  for (int k0 = 0; k0 < Kd; k0 += 32) {
    __syncthreads();                     // prev compute done before overwrite
    GLD16(pA1, dA1);
    GLD16(pA2, dA2);
    GLD16(pB1, dB1);
    GLD16(pB2, dB2);
    pA1 += 32; pA2 += 32; pB1 += 32; pB2 += 32;
    __syncthreads();                     // vmcnt(0) drain: tile ready
    bf16x8 af[4], bfr[4];
#pragma unroll
    for (int i = 0; i < 4; ++i) {
      af[i]  = ldb8(As + (wr * 4 + i) * 512 + lane * 8);
      bfr[i] = ldb8(Bs + (wc * 4 + i) * 512 + lane * 8);
    }
#pragma unroll
    for (int i = 0; i < 4; ++i)
#pragma unroll
      for (int j = 0; j < 4; ++j)
        acc[i][j] = __builtin_amdgcn_mfma_f32_16x16x32_bf16(af[i], bfr[j], acc[i][j], 0, 0, 0);
  }

  if (MODE == 1) {
#pragma unroll
    for (int i = 0; i < 4; ++i)
#pragma unroll
      for (int j = 0; j < 4; ++j)
#pragma unroll
        for (int r = 0; r < 4; ++r) {
          int m = m0 + wr * 64 + i * 16 + lg * 4 + r;
          int n = n0 + wc * 64 + j * 16 + l16;
          Cf[(size_t)m * N + n] = acc[i][j][r];
        }
  } else {
    int head = n0 >> 7;
#pragma unroll
    for (int i = 0; i < 4; ++i)
#pragma unroll
      for (int j = 0; j < 4; ++j)
#pragma unroll
        for (int r = 0; r < 4; ++r) {
          int m = m0 + wr * 64 + i * 16 + lg * 4 + r;
          int d = wc * 64 + j * 16 + l16;
          int b = m >> 11, s = m & (S_ - 1);
          u16 val = f2b(acc[i][j][r]);
          if (head < NH_) {
            Qb[(((size_t)b * NH_ + head) * S_ + s) * HD_ + d] = val;
          } else if (head < NH_ + NKV_) {
            Kb[(((size_t)b * NKV_ + (head - NH_)) * S_ + s) * HD_ + d] = val;
          } else {
            Vb[(((size_t)b * NKV_ + (head - NH_ - NKV_)) * HD_ + d) * S_ + s] = val;
          }
        }
  }
}

// ---------- kernel 4: RoPE in-place on [rows][128] bf16, one wave per row ----------
__global__ __launch_bounds__(256) void k_rope(u16* __restrict__ buf, const int* __restrict__ pos,
                                              const float* __restrict__ ct, const float* __restrict__ st,
                                              int H, int rows) {
  int wave = threadIdx.x >> 6, lane = threadIdx.x & 63;
  int row = blockIdx.x * 4 + wave;
  if (row >= rows) return;
  int s = row & (S_ - 1);
  int b = row / (H * S_);
  int p = pos[b * S_ + s];
  size_t base = (size_t)row * HD_;
  float x1 = b2f(buf[base + lane]);
  float x2 = b2f(buf[base + 64 + lane]);
  float c  = ct[(size_t)p * HD_ + lane];
  float sn = st[(size_t)p * HD_ + lane];
  buf[base + lane]      = f2b(x1 * c - x2 * sn);
  buf[base + 64 + lane] = f2b(x2 * c + x1 * sn);
}

// ---------- kernel 5: causal GQA flash attention (v2) ----------
__global__ __launch_bounds__(256, 4) void k_attn(const u16* __restrict__ Q,
                                                 const u16* __restrict__ K,
                                                 const u16* __restrict__ Vt,
                                                 u16* __restrict__ Ob) {
  __shared__ __align__(16) char smem[40960];
  const int VS_OFF = 16384, PS_OFF = 32768;

  int bid = blockIdx.x;
  int pid = bid & 15;
  int h   = (bid >> 4) & 31;
  int b   = bid >> 9;
  int kvh = h >> 2;
  int tid = threadIdx.x;
  int wave = tid >> 6, lane = tid & 63;
  int lg = lane >> 4, l16 = lane & 15;
  int lsw = (l16 & 7) << 4;

  const u16* Qp = Q  + (((size_t)b * NH_  + h)   * S_) * HD_;
  const u16* Kp = K  + (((size_t)b * NKV_ + kvh) * S_) * HD_;
  const u16* Vp = Vt + (((size_t)b * NKV_ + kvh) * HD_) * S_;

  for (int pass = 0; pass < 2; ++pass) {
    int qt = pass ? (31 - pid) : pid;
    int q0 = qt * 64 + wave * 16;
    int qg = q0 + l16;

    bf16x8 qf[4];
#pragma unroll
    for (int c = 0; c < 4; ++c)
      qf[c] = ldb8(&Qp[(size_t)qg * HD_ + c * 32 + lg * 8]);

    f32x4 oacc[8] = {};
    float mrun = -1e30f, lrun = 0.f;

    int nt = qt + 1;
    for (int tI = 0; tI < nt; ++tI) {
      int kb = tI * 64;
      __syncthreads();
#pragma unroll
      for (int i = 0; i < 4; ++i) {
        int ci = i * 256 + tid;
        int r = ci >> 4, ch = ci & 15;
        u16x8 v = *(const u16x8*)&Kp[(size_t)(kb + r) * HD_ + ch * 8];
        *(u16x8*)(smem + r * 256 + ((ch * 16) ^ ((r & 7) << 4))) = v;
      }
#pragma unroll
      for (int i = 0; i < 4; ++i) {
        int ci = i * 256 + tid;
        int r = ci >> 3, ch = ci & 7;
        u16x8 v = *(const u16x8*)&Vp[(size_t)r * S_ + kb + ch * 8];
        *(u16x8*)(smem + VS_OFF + r * 128 + ((ch * 16) ^ ((r & 7) << 4))) = v;
      }
      __syncthreads();

      f32x4 sc[4] = {};
#pragma unroll
      for (int c = 0; c < 4; ++c) {
#pragma unroll
        for (int n = 0; n < 4; ++n) {
          bf16x8 kf = ldb8b(smem + (n * 16 + l16) * 256 + ((c * 64 + lg * 16) ^ lsw));
          sc[n] = __builtin_amdgcn_mfma_f32_16x16x32_bf16(kf, qf[c], sc[n], 0, 0, 0);
        }
      }

      bool diag = (tI == qt);
      float mx = -1e30f;
#pragma unroll
      for (int n = 0; n < 4; ++n)
#pragma unroll
        for (int r = 0; r < 4; ++r) {
          float v = sc[n][r];
          int key = kb + n * 16 + lg * 4 + r;
          if (diag && key > qg) v = -1e30f;
          sc[n][r] = v;
          mx = fmaxf(mx, v);
        }
      mx = fmaxf(mx, __shfl_xor(mx, 16));
      mx = fmaxf(mx, __shfl_xor(mx, 32));
      float mnew = fmaxf(mrun, mx * SCALE_);
      float alpha = __expf(mrun - mnew);
      float ps = 0.f;
#pragma unroll
      for (int n = 0; n < 4; ++n) {
        u16x4 pk;
#pragma unroll
        for (int r = 0; r < 4; ++r) {
          float p = __expf(fmaf(sc[n][r], SCALE_, -mnew));
          ps += p;
          pk[r] = f2b(p);
        }
        *(u16x4*)(smem + PS_OFF + wave * 2048 + l16 * 128 + ((n * 32 + lg * 8) ^ lsw)) = pk;
      }
      ps += __shfl_xor(ps, 16);
      ps += __shfl_xor(ps, 32);
      lrun = lrun * alpha + ps;
      mrun = mnew;

      float ar[4];
#pragma unroll
      for (int r = 0; r < 4; ++r) ar[r] = __shfl(alpha, lg * 4 + r);
#pragma unroll
      for (int ns = 0; ns < 8; ++ns)
#pragma unroll
        for (int r = 0; r < 4; ++r) oacc[ns][r] *= ar[r];

#pragma unroll
      for (int ck = 0; ck < 2; ++ck) {
        bf16x8 pa = ldb8b(smem + PS_OFF + wave * 2048 + l16 * 128 + ((ck * 64 + lg * 16) ^ lsw));
#pragma unroll
        for (int ns = 0; ns < 8; ++ns) {
          bf16x8 vf = ldb8b(smem + VS_OFF + (ns * 16 + l16) * 128 + ((ck * 64 + lg * 16) ^ lsw));
          oacc[ns] = __builtin_amdgcn_mfma_f32_16x16x32_bf16(pa, vf, oacc[ns], 0, 0, 0);
        }
      }
    }

    float lr[4];
#pragma unroll
    for (int r = 0; r < 4; ++r) lr[r] = 1.0f / __shfl(lrun, lg * 4 + r);
#pragma unroll
    for (int ns = 0; ns < 8; ++ns)
#pragma unroll
      for (int r = 0; r < 4; ++r) {
        int q = q0 + lg * 4 + r;
        Ob[((size_t)(b * S_) + q) * (NH_ * HD_) + h * HD_ + ns * 16 + l16] =
            f2b(oacc[ns][r] * lr[r]);
      }
  }
}

// ---------- launch ----------
extern "C" void kernel_launch(void* const* d_in, const int* in_sizes, int n_in,
                              void* d_out, int out_size, void* d_ws, size_t ws_size,
                              hipStream_t stream) {
  const float* hs  = (const float*)d_in[0];
  const int*   pos = (const int*)d_in[1];
  const float* ct  = (const float*)d_in[2];
  const float* st  = (const float*)d_in[3];
  const float* Wq  = (const float*)d_in[4];
  const float* Wk  = (const float*)d_in[5];
  const float* Wv  = (const float*)d_in[6];
  const float* Wo  = (const float*)d_in[7];
  float* out = (float*)d_out;

  char* w = (char*)d_ws;
  u16* Xb    = (u16*)(w);                       // [4096][4096]
  u16* WqkvT = (u16*)(w + 33554432ull);         // [6144][4096]
  u16* WoT   = (u16*)(w + 83886080ull);         // [4096][4096]
  u16* Qb    = (u16*)(w + 117440512ull);        // [2][32][2048][128]
  u16* Kb    = (u16*)(w + 150994944ull);        // [2][8][2048][128]
  u16* Vb    = (u16*)(w + 159383552ull);        // [2][8][128][2048]
  u16* Attb  = (u16*)(w + 167772160ull);        // [4096][4096]

  k_convx<<<16384, 256, 0, stream>>>(hs, Xb, 4194304);
  k_convT<<<dim3(64, 64), 256, 0, stream>>>(Wq, WqkvT, 4096, 4096);
  k_convT<<<dim3(64, 16), 256, 0, stream>>>(Wk, WqkvT + (size_t)4096 * 4096, 1024, 4096);
  k_convT<<<dim3(64, 16), 256, 0, stream>>>(Wv, WqkvT + (size_t)5120 * 4096, 1024, 4096);
  k_convT<<<dim3(64, 64), 256, 0, stream>>>(Wo, WoT, 4096, 4096);
  k_gemm<0><<<dim3(48, 32), 256, 0, stream>>>(Xb, WqkvT, nullptr, Qb, Kb, Vb, 4096, NTOT_, 4096);
  k_rope<<<32768, 256, 0, stream>>>(Qb, pos, ct, st, NH_, B_ * NH_ * S_);
  k_rope<<<8192, 256, 0, stream>>>(Kb, pos, ct, st, NKV_, B_ * NKV_ * S_);
  k_attn<<<1024, 256, 0, stream>>>(Qb, Kb, Vb, Attb);
  k_gemm<1><<<dim3(32, 32), 256, 0, stream>>>(Attb, WoT, out, nullptr, nullptr, nullptr, 4096, 4096, 4096);
}

// Round 5
// 669.961 us; speedup vs baseline: 1.3538x; 1.3538x over previous
//
#include <hip/hip_runtime.h>
#include <stdint.h>

typedef unsigned short u16;
typedef __bf16 bf16x8 __attribute__((ext_vector_type(8)));
typedef unsigned short u16x8 __attribute__((ext_vector_type(8)));
typedef unsigned short u16x4 __attribute__((ext_vector_type(4)));
typedef float f32x4 __attribute__((ext_vector_type(4)));

#define B_ 2
#define S_ 2048
#define HID_ 4096
#define NH_ 32
#define NKV_ 8
#define HD_ 128
#define NTOT_ 6144  // NH*HD + 2*NKV*HD
#define SCALE_ 0.08838834764831845f

// async global->LDS, 16B per lane, wave-uniform LDS base + lane*16 linear dest
#define GLD16(gp, lp)                                                     \
  __builtin_amdgcn_global_load_lds(                                       \
      (__attribute__((address_space(1))) void*)(gp),                      \
      (__attribute__((address_space(3))) void*)(lp), 16, 0, 0)

// ---------- bf16 helpers ----------
__device__ __forceinline__ u16 f2b(float f) {
  union { float f; uint32_t u; } v; v.f = f;
  uint32_t u = v.u;
  u = u + 0x7fffu + ((u >> 16) & 1u);   // round-to-nearest-even
  return (u16)(u >> 16);
}
__device__ __forceinline__ float b2f(u16 s) {
  union { uint32_t u; float f; } v; v.u = ((uint32_t)s) << 16;
  return v.f;
}
__device__ __forceinline__ bf16x8 ldb8(const u16* p) {
  u16x8 u = *(const u16x8*)p;
  return __builtin_bit_cast(bf16x8, u);
}
__device__ __forceinline__ bf16x8 ldb8b(const char* p) {
  u16x8 u = *(const u16x8*)p;
  return __builtin_bit_cast(bf16x8, u);
}

// ---------- kernel 1: f32 -> bf16 (vectorized) ----------
__global__ __launch_bounds__(256) void k_convx(const float* __restrict__ src,
                                               u16* __restrict__ dst, int n4) {
  int i = blockIdx.x * 256 + threadIdx.x;
  if (i >= n4) return;
  const float4 v = ((const float4*)src)[i];
  u16x4 o = { f2b(v.x), f2b(v.y), f2b(v.z), f2b(v.w) };
  *(u16x4*)(dst + (size_t)i * 4) = o;
}

// ---------- kernel 2: transpose-convert W f32 [Kd][N] -> bf16 [N][Kd] ----------
__global__ __launch_bounds__(256) void k_convT(const float* __restrict__ src,
                                               u16* __restrict__ dst, int N, int Kd) {
  __shared__ u16 tile[64][65];
  int k0 = blockIdx.x * 64, n0 = blockIdx.y * 64;
  int t = threadIdx.x;
  int rr = t >> 4;          // 0..15
  int cc = (t & 15) * 4;    // 0..60
#pragma unroll
  for (int p = 0; p < 4; ++p) {
    int r = p * 16 + rr;
    float4 v = *(const float4*)&src[(size_t)(k0 + r) * N + n0 + cc];
    tile[cc + 0][r] = f2b(v.x);
    tile[cc + 1][r] = f2b(v.y);
    tile[cc + 2][r] = f2b(v.z);
    tile[cc + 3][r] = f2b(v.w);
  }
  __syncthreads();
#pragma unroll
  for (int p = 0; p < 4; ++p) {
    int n = p * 16 + rr;
    u16x4 o = { tile[n][cc], tile[n][cc + 1], tile[n][cc + 2], tile[n][cc + 3] };
    *(u16x4*)&dst[(size_t)(n0 + n) * Kd + k0 + cc] = o;
  }
}

// ---------- kernel 3: bf16 GEMM v3 — 256x256 tile, BK=32, 4-buffer ring ----------
// Deep pipeline: prefetch 3 K-tiles ahead (counted vmcnt, never 0 in steady
// state), 1 barrier + 1 vmcnt per K-tile. 8 waves (2M x 4N), wave-tile 128x64,
// acc[8][4]. LDS 4 x (A 16KB + B 16KB) = 128KB.
// LDS group layout (16 rows x 32 k = 1KB per group): both-sides involution
//   off(r,c) = r*64 + ((c ^ ((r>>1)&3))<<4)
// staged by gload_lds linear dest with lane i -> (row i>>2, chunk (i&3)^((i>>3)&3))
// -> global quarter-wave = 4 contiguous 64B sectors; frag read quarter-wave
// spans all 8 bank-quads (2-way = free).
// A: [M][Kd] bf16 row-major. Bt: [N][Kd] bf16 (B transposed). Requires Kd%32==0,
// Kd/32 >= 4, grid blocks % 8 == 0.
// MODE 0: QKV epilogue scatter. MODE 1: f32 C output [M][N].
template <int MODE>
__global__ __launch_bounds__(512, 2) void k_gemm(const u16* __restrict__ A,
                                                 const u16* __restrict__ Bt,
                                                 float* __restrict__ Cf,
                                                 u16* __restrict__ Qb,
                                                 u16* __restrict__ Kb,
                                                 u16* __restrict__ Vb,
                                                 int M, int N, int Kd) {
  __shared__ __align__(16) char smem[131072];
  const int NT = Kd >> 5;

  // bijective XCD swizzle (grid size divisible by 8)
  int nwg = gridDim.x * gridDim.y;
  int orig = blockIdx.y * gridDim.x + blockIdx.x;
  int cpx = nwg >> 3;
  int swz = (orig & 7) * cpx + (orig >> 3);
  int bx = swz % gridDim.x, by = swz / gridDim.x;
  int m0 = by * 256, n0 = bx * 256;

  int t = threadIdx.x, lane = t & 63, wave = t >> 6;
  int wr = wave >> 2, wc = wave & 3;           // 2M x 4N wave grid
  int lg = lane >> 4, l16 = lane & 15;
  int loff = l16 * 64 + ((lg ^ ((l16 >> 1) & 3)) << 4);  // frag-read lane offset

  // staging source (lane i -> row i>>2, chunk (i&3)^((i>>3)&3))
  int srow = lane >> 2;
  int schk = (lane & 3) ^ ((lane >> 3) & 3);
  const u16* sA0 = A  + (size_t)(m0 + wave * 16 + srow) * Kd + schk * 8;
  const u16* sA1 = sA0 + (size_t)128 * Kd;
  const u16* sB0 = Bt + (size_t)(n0 + wave * 16 + srow) * Kd + schk * 8;
  const u16* sB1 = sB0 + (size_t)128 * Kd;

  f32x4 acc[8][4] = {};

#define STAGE_A(kt) do { char* dst_ = smem + ((kt) & 3) * 32768 + wave * 1024;          \
    GLD16(sA0 + (size_t)(kt) * 32, dst_); GLD16(sA1 + (size_t)(kt) * 32, dst_ + 8192); } while (0)
#define STAGE_B(kt) do { char* dst_ = smem + ((kt) & 3) * 32768 + 16384 + wave * 1024;  \
    GLD16(sB0 + (size_t)(kt) * 32, dst_); GLD16(sB1 + (size_t)(kt) * 32, dst_ + 8192); } while (0)

  // prologue: 3 K-tiles in flight, wait for kt0 (12 outstanding -> 8)
  STAGE_A(0); STAGE_B(0);
  STAGE_A(1); STAGE_B(1);
  STAGE_A(2); STAGE_B(2);
  asm volatile("s_waitcnt vmcnt(8)" ::: "memory");
  __syncthreads();

  for (int kt = 0; kt < NT; ++kt) {
    char* Ab = smem + (kt & 3) * 32768;
    char* Bb = Ab + 16384;
    bf16x8 bfr[4], af[4];
#pragma unroll
    for (int j = 0; j < 4; ++j) bfr[j] = ldb8b(Bb + (wc * 4 + j) * 1024 + loff);
#pragma unroll
    for (int i = 0; i < 4; ++i) af[i] = ldb8b(Ab + (wr * 8 + i) * 1024 + loff);
    if (kt + 3 < NT) STAGE_A(kt + 3);
    __builtin_amdgcn_s_setprio(1);
#pragma unroll
    for (int i = 0; i < 4; ++i)
#pragma unroll
      for (int j = 0; j < 4; ++j)
        acc[i][j] = __builtin_amdgcn_mfma_f32_16x16x32_bf16(af[i], bfr[j], acc[i][j], 0, 0, 0);
    __builtin_amdgcn_s_setprio(0);
#pragma unroll
    for (int i = 0; i < 4; ++i) af[i] = ldb8b(Ab + (wr * 8 + 4 + i) * 1024 + loff);
    if (kt + 3 < NT) STAGE_B(kt + 3);
    __builtin_amdgcn_s_setprio(1);
#pragma unroll
    for (int i = 0; i < 4; ++i)
#pragma unroll
      for (int j = 0; j < 4; ++j)
        acc[4 + i][j] = __builtin_amdgcn_mfma_f32_16x16x32_bf16(af[i], bfr[j], acc[4 + i][j], 0, 0, 0);
    __builtin_amdgcn_s_setprio(0);
    // boundary: ensure kt+1's buffer complete across all waves.
    // outstanding (this wave): kt+1(4, oldest) + kt+2(4) + kt+3(4 if issued)
    if (kt < NT - 3) {
      asm volatile("s_waitcnt vmcnt(8)" ::: "memory");
      __syncthreads();
    } else if (kt == NT - 3) {
      asm volatile("s_waitcnt vmcnt(4)" ::: "memory");
      __syncthreads();
    } else if (kt == NT - 2) {
      asm volatile("s_waitcnt vmcnt(0)" ::: "memory");
      __syncthreads();
    }
  }
#undef STAGE_A
#undef STAGE_B

  if (MODE == 1) {
#pragma unroll
    for (int i = 0; i < 8; ++i)
#pragma unroll
      for (int j = 0; j < 4; ++j)
#pragma unroll
        for (int r = 0; r < 4; ++r) {
          int m = m0 + wr * 128 + i * 16 + lg * 4 + r;
          int n = n0 + wc * 64 + j * 16 + l16;
          Cf[(size_t)m * N + n] = acc[i][j][r];
        }
  } else {
    int slice = (n0 >> 7) + (wc >> 1);       // 128-wide head slice, wave-uniform
#pragma unroll
    for (int i = 0; i < 8; ++i)
#pragma unroll
      for (int j = 0; j < 4; ++j)
#pragma unroll
        for (int r = 0; r < 4; ++r) {
          int m = m0 + wr * 128 + i * 16 + lg * 4 + r;
          int d = ((wc & 1) << 6) + j * 16 + l16;
          int b = m >> 11, s = m & (S_ - 1);
          u16 val = f2b(acc[i][j][r]);
          if (slice < NH_) {
            Qb[(((size_t)b * NH_ + slice) * S_ + s) * HD_ + d] = val;
          } else if (slice < NH_ + NKV_) {
            Kb[(((size_t)b * NKV_ + (slice - NH_)) * S_ + s) * HD_ + d] = val;
          } else {
            Vb[(((size_t)b * NKV_ + (slice - NH_ - NKV_)) * HD_ + d) * S_ + s] = val;
          }
        }
  }
}

// ---------- kernel 4: RoPE in-place on [rows][128] bf16, one wave per row ----------
__global__ __launch_bounds__(256) void k_rope(u16* __restrict__ buf, const int* __restrict__ pos,
                                              const float* __restrict__ ct, const float* __restrict__ st,
                                              int H, int rows) {
  int wave = threadIdx.x >> 6, lane = threadIdx.x & 63;
  int row = blockIdx.x * 4 + wave;
  if (row >= rows) return;
  int s = row & (S_ - 1);
  int b = row / (H * S_);
  int p = pos[b * S_ + s];
  size_t base = (size_t)row * HD_;
  float x1 = b2f(buf[base + lane]);
  float x2 = b2f(buf[base + 64 + lane]);
  float c  = ct[(size_t)p * HD_ + lane];
  float sn = st[(size_t)p * HD_ + lane];
  buf[base + lane]      = f2b(x1 * c - x2 * sn);
  buf[base + 64 + lane] = f2b(x2 * c + x1 * sn);
}

// ---------- kernel 5: causal GQA flash attention (v2, unchanged) ----------
__global__ __launch_bounds__(256, 4) void k_attn(const u16* __restrict__ Q,
                                                 const u16* __restrict__ K,
                                                 const u16* __restrict__ Vt,
                                                 u16* __restrict__ Ob) {
  __shared__ __align__(16) char smem[40960];
  const int VS_OFF = 16384, PS_OFF = 32768;

  int bid = blockIdx.x;
  int pid = bid & 15;
  int h   = (bid >> 4) & 31;
  int b   = bid >> 9;
  int kvh = h >> 2;
  int tid = threadIdx.x;
  int wave = tid >> 6, lane = tid & 63;
  int lg = lane >> 4, l16 = lane & 15;
  int lsw = (l16 & 7) << 4;

  const u16* Qp = Q  + (((size_t)b * NH_  + h)   * S_) * HD_;
  const u16* Kp = K  + (((size_t)b * NKV_ + kvh) * S_) * HD_;
  const u16* Vp = Vt + (((size_t)b * NKV_ + kvh) * HD_) * S_;

  for (int pass = 0; pass < 2; ++pass) {
    int qt = pass ? (31 - pid) : pid;
    int q0 = qt * 64 + wave * 16;
    int qg = q0 + l16;

    bf16x8 qf[4];
#pragma unroll
    for (int c = 0; c < 4; ++c)
      qf[c] = ldb8(&Qp[(size_t)qg * HD_ + c * 32 + lg * 8]);

    f32x4 oacc[8] = {};
    float mrun = -1e30f, lrun = 0.f;

    int nt = qt + 1;
    for (int tI = 0; tI < nt; ++tI) {
      int kb = tI * 64;
      __syncthreads();
#pragma unroll
      for (int i = 0; i < 4; ++i) {
        int ci = i * 256 + tid;
        int r = ci >> 4, ch = ci & 15;
        u16x8 v = *(const u16x8*)&Kp[(size_t)(kb + r) * HD_ + ch * 8];
        *(u16x8*)(smem + r * 256 + ((ch * 16) ^ ((r & 7) << 4))) = v;
      }
#pragma unroll
      for (int i = 0; i < 4; ++i) {
        int ci = i * 256 + tid;
        int r = ci >> 3, ch = ci & 7;
        u16x8 v = *(const u16x8*)&Vp[(size_t)r * S_ + kb + ch * 8];
        *(u16x8*)(smem + VS_OFF + r * 128 + ((ch * 16) ^ ((r & 7) << 4))) = v;
      }
      __syncthreads();

      f32x4 sc[4] = {};
#pragma unroll
      for (int c = 0; c < 4; ++c) {
#pragma unroll
        for (int n = 0; n < 4; ++n) {
          bf16x8 kf = ldb8b(smem + (n * 16 + l16) * 256 + ((c * 64 + lg * 16) ^ lsw));
          sc[n] = __builtin_amdgcn_mfma_f32_16x16x32_bf16(kf, qf[c], sc[n], 0, 0, 0);
        }
      }

      bool diag = (tI == qt);
      float mx = -1e30f;
#pragma unroll
      for (int n = 0; n < 4; ++n)
#pragma unroll
        for (int r = 0; r < 4; ++r) {
          float v = sc[n][r];
          int key = kb + n * 16 + lg * 4 + r;
          if (diag && key > qg) v = -1e30f;
          sc[n][r] = v;
          mx = fmaxf(mx, v);
        }
      mx = fmaxf(mx, __shfl_xor(mx, 16));
      mx = fmaxf(mx, __shfl_xor(mx, 32));
      float mnew = fmaxf(mrun, mx * SCALE_);
      float alpha = __expf(mrun - mnew);
      float ps = 0.f;
#pragma unroll
      for (int n = 0; n < 4; ++n) {
        u16x4 pk;
#pragma unroll
        for (int r = 0; r < 4; ++r) {
          float p = __expf(fmaf(sc[n][r], SCALE_, -mnew));
          ps += p;
          pk[r] = f2b(p);
        }
        *(u16x4*)(smem + PS_OFF + wave * 2048 + l16 * 128 + ((n * 32 + lg * 8) ^ lsw)) = pk;
      }
      ps += __shfl_xor(ps, 16);
      ps += __shfl_xor(ps, 32);
      lrun = lrun * alpha + ps;
      mrun = mnew;

      float ar[4];
#pragma unroll
      for (int r = 0; r < 4; ++r) ar[r] = __shfl(alpha, lg * 4 + r);
#pragma unroll
      for (int ns = 0; ns < 8; ++ns)
#pragma unroll
        for (int r = 0; r < 4; ++r) oacc[ns][r] *= ar[r];

#pragma unroll
      for (int ck = 0; ck < 2; ++ck) {
        bf16x8 pa = ldb8b(smem + PS_OFF + wave * 2048 + l16 * 128 + ((ck * 64 + lg * 16) ^ lsw));
#pragma unroll
        for (int ns = 0; ns < 8; ++ns) {
          bf16x8 vf = ldb8b(smem + VS_OFF + (ns * 16 + l16) * 128 + ((ck * 64 + lg * 16) ^ lsw));
          oacc[ns] = __builtin_amdgcn_mfma_f32_16x16x32_bf16(pa, vf, oacc[ns], 0, 0, 0);
        }
      }
    }

    float lr[4];
#pragma unroll
    for (int r = 0; r < 4; ++r) lr[r] = 1.0f / __shfl(lrun, lg * 4 + r);
#pragma unroll
    for (int ns = 0; ns < 8; ++ns)
#pragma unroll
      for (int r = 0; r < 4; ++r) {
        int q = q0 + lg * 4 + r;
        Ob[((size_t)(b * S_) + q) * (NH_ * HD_) + h * HD_ + ns * 16 + l16] =
            f2b(oacc[ns][r] * lr[r]);
      }
  }
}

// ---------- launch ----------
extern "C" void kernel_launch(void* const* d_in, const int* in_sizes, int n_in,
                              void* d_out, int out_size, void* d_ws, size_t ws_size,
                              hipStream_t stream) {
  const float* hs  = (const float*)d_in[0];
  const int*   pos = (const int*)d_in[1];
  const float* ct  = (const float*)d_in[2];
  const float* st  = (const float*)d_in[3];
  const float* Wq  = (const float*)d_in[4];
  const float* Wk  = (const float*)d_in[5];
  const float* Wv  = (const float*)d_in[6];
  const float* Wo  = (const float*)d_in[7];
  float* out = (float*)d_out;

  char* w = (char*)d_ws;
  u16* Xb    = (u16*)(w);                       // [4096][4096]
  u16* WqkvT = (u16*)(w + 33554432ull);         // [6144][4096]
  u16* WoT   = (u16*)(w + 83886080ull);         // [4096][4096]
  u16* Qb    = (u16*)(w + 117440512ull);        // [2][32][2048][128]
  u16* Kb    = (u16*)(w + 150994944ull);        // [2][8][2048][128]
  u16* Vb    = (u16*)(w + 159383552ull);        // [2][8][128][2048]
  u16* Attb  = (u16*)(w + 167772160ull);        // [4096][4096]

  k_convx<<<16384, 256, 0, stream>>>(hs, Xb, 4194304);
  k_convT<<<dim3(64, 64), 256, 0, stream>>>(Wq, WqkvT, 4096, 4096);
  k_convT<<<dim3(64, 16), 256, 0, stream>>>(Wk, WqkvT + (size_t)4096 * 4096, 1024, 4096);
  k_convT<<<dim3(64, 16), 256, 0, stream>>>(Wv, WqkvT + (size_t)5120 * 4096, 1024, 4096);
  k_convT<<<dim3(64, 64), 256, 0, stream>>>(Wo, WoT, 4096, 4096);
  k_gemm<0><<<dim3(24, 16), 512, 0, stream>>>(Xb, WqkvT, nullptr, Qb, Kb, Vb, 4096, NTOT_, 4096);
  k_rope<<<32768, 256, 0, stream>>>(Qb, pos, ct, st, NH_, B_ * NH_ * S_);
  k_rope<<<8192, 256, 0, stream>>>(Kb, pos, ct, st, NKV_, B_ * NKV_ * S_);
  k_attn<<<1024, 256, 0, stream>>>(Qb, Kb, Vb, Attb);
  k_gemm<1><<<dim3(16, 16), 512, 0, stream>>>(Attb, WoT, out, nullptr, nullptr, nullptr, 4096, 4096, 4096);
}

// Round 6
// 636.808 us; speedup vs baseline: 1.4242x; 1.0521x over previous
//
#include <hip/hip_runtime.h>
#include <stdint.h>

typedef unsigned short u16;
typedef __bf16 bf16x8 __attribute__((ext_vector_type(8)));
typedef unsigned short u16x8 __attribute__((ext_vector_type(8)));
typedef unsigned short u16x4 __attribute__((ext_vector_type(4)));
typedef float f32x4 __attribute__((ext_vector_type(4)));

#define B_ 2
#define S_ 2048
#define HID_ 4096
#define NH_ 32
#define NKV_ 8
#define HD_ 128
#define NTOT_ 6144
#define SCALE_ 0.08838834764831845f

#define GLD16(gp, lp)                                                     \
  __builtin_amdgcn_global_load_lds(                                       \
      (__attribute__((address_space(1))) void*)(gp),                      \
      (__attribute__((address_space(3))) void*)(lp), 16, 0, 0)

// ---------- bf16 helpers ----------
__device__ __forceinline__ u16 f2b(float f) {
  union { float f; uint32_t u; } v; v.f = f;
  uint32_t u = v.u;
  u = u + 0x7fffu + ((u >> 16) & 1u);
  return (u16)(u >> 16);
}
__device__ __forceinline__ float b2f(u16 s) {
  union { uint32_t u; float f; } v; v.u = ((uint32_t)s) << 16;
  return v.f;
}
__device__ __forceinline__ bf16x8 ldb8(const u16* p) {
  u16x8 u = *(const u16x8*)p;
  return __builtin_bit_cast(bf16x8, u);
}
__device__ __forceinline__ bf16x8 ldb8b(const char* p) {
  u16x8 u = *(const u16x8*)p;
  return __builtin_bit_cast(bf16x8, u);
}

// ---------- kernel 1: f32 -> bf16 ----------
__global__ __launch_bounds__(256) void k_convx(const float* __restrict__ src,
                                               u16* __restrict__ dst, int n4) {
  int i = blockIdx.x * 256 + threadIdx.x;
  if (i >= n4) return;
  const float4 v = ((const float4*)src)[i];
  u16x4 o = { f2b(v.x), f2b(v.y), f2b(v.z), f2b(v.w) };
  *(u16x4*)(dst + (size_t)i * 4) = o;
}

// ---------- kernel 2: transpose-convert W f32 [Kd][N] -> bf16 [N][Kd] ----------
__global__ __launch_bounds__(256) void k_convT(const float* __restrict__ src,
                                               u16* __restrict__ dst, int N, int Kd) {
  __shared__ u16 tile[64][65];
  int k0 = blockIdx.x * 64, n0 = blockIdx.y * 64;
  int t = threadIdx.x;
  int rr = t >> 4;
  int cc = (t & 15) * 4;
#pragma unroll
  for (int p = 0; p < 4; ++p) {
    int r = p * 16 + rr;
    float4 v = *(const float4*)&src[(size_t)(k0 + r) * N + n0 + cc];
    tile[cc + 0][r] = f2b(v.x);
    tile[cc + 1][r] = f2b(v.y);
    tile[cc + 2][r] = f2b(v.z);
    tile[cc + 3][r] = f2b(v.w);
  }
  __syncthreads();
#pragma unroll
  for (int p = 0; p < 4; ++p) {
    int n = p * 16 + rr;
    u16x4 o = { tile[n][cc], tile[n][cc + 1], tile[n][cc + 2], tile[n][cc + 3] };
    *(u16x4*)&dst[(size_t)(n0 + n) * Kd + k0 + cc] = o;
  }
}

// ---------- GEMM core: 256x256 tile, BK=64, 8-phase (4/K-tile) schedule ----------
// 8 waves (2M x 4N), wave tile 128x64, acc[8][4]. LDS: 2 buffers x (A 32KB + B 32KB).
// Each 32-k half staged as 16 row-groups of 1KB: group g holds rows g*16..+15,
// chunk c of row r stored at phys c ^ ((r>>1)&3) (involution; staging source is
// XOR-permuted within each 64B segment -> coalescing intact; frag reads 2-way = free;
// verified 0 bank conflicts in R5).
// Phase schedule per K-tile t: P1(kc0,ms0)+stageA0(t+1), P2(kc0,ms1)+stageB0(t+1)
//   +vmcnt(4), P3(kc1,ms0)+stageA1(t+1), P4(kc1,ms1)+stageB1(t+1)+vmcnt(4).
// Wait proof: at each vmcnt(4)+barrier the 4 oldest per-wave loads (= the two
// halves read next) are forced complete; overwrites land >=2 barriers after the
// last read of the overwritten region.
template <int MODE>
__device__ __forceinline__ void gemm_body(const u16* __restrict__ A,
                                          const u16* __restrict__ Bt,
                                          float* __restrict__ Cf,
                                          u16* __restrict__ Qb,
                                          u16* __restrict__ Kb,
                                          u16* __restrict__ Vb,
                                          int M, int N, int Kd) {
  __shared__ __align__(16) char smem[131072];
  const int NT = Kd >> 6;

  // bijective XCD swizzle (grid % 8 == 0)
  int nwg = gridDim.x * gridDim.y;
  int orig = blockIdx.y * gridDim.x + blockIdx.x;
  int cpx = nwg >> 3;
  int swz = (orig & 7) * cpx + (orig >> 3);
  int bx = swz % gridDim.x, by = swz / gridDim.x;
  int m0 = by * 256, n0 = bx * 256;

  int t = threadIdx.x, lane = t & 63, wave = t >> 6;
  int wr = wave >> 2, wc = wave & 3;
  int lg = lane >> 4, l16 = lane & 15;
  int loff = l16 * 64 + ((lg ^ ((l16 >> 1) & 3)) << 4);
  int srow = lane >> 2, schk = (lane & 3) ^ ((lane >> 3) & 3);

  const u16* Asrc = A  + (size_t)(m0 + wave * 32 + srow) * Kd + schk * 8;
  const u16* Bsrc = Bt + (size_t)(n0 + wave * 32 + srow) * Kd + schk * 8;

  f32x4 acc[8][4] = {};

#define STG_A(kt, kc) do {                                                          \
    char* d_ = smem + (((kt) & 1) << 16) + ((kc) << 14) + (wave << 11);             \
    const u16* s_ = Asrc + (size_t)(kt) * 64 + (kc) * 32;                           \
    GLD16(s_, d_); GLD16(s_ + (size_t)16 * Kd, d_ + 1024); } while (0)
#define STG_B(kt, kc) do {                                                          \
    char* d_ = smem + (((kt) & 1) << 16) + 32768 + ((kc) << 14) + (wave << 11);     \
    const u16* s_ = Bsrc + (size_t)(kt) * 64 + (kc) * 32;                           \
    GLD16(s_, d_); GLD16(s_ + (size_t)16 * Kd, d_ + 1024); } while (0)

  // prologue: full tile 0
  STG_A(0, 0); STG_B(0, 0); STG_A(0, 1); STG_B(0, 1);
  asm volatile("s_waitcnt vmcnt(0)" ::: "memory");
  __syncthreads();

  for (int kt = 0; kt < NT; ++kt) {
    const char* bufA = smem + ((kt & 1) << 16);
    const char* bufB = bufA + 32768;
    bool pf = (kt + 1 < NT);
    bf16x8 bfr[4], af[4];

    // ---- P1: kc0, ms0 ----
#pragma unroll
    for (int j = 0; j < 4; ++j) bfr[j] = ldb8b(bufB + ((wc * 4 + j) << 10) + loff);
#pragma unroll
    for (int i = 0; i < 4; ++i) af[i] = ldb8b(bufA + ((wr * 8 + i) << 10) + loff);
    if (pf) STG_A(kt + 1, 0);
    __builtin_amdgcn_s_barrier();
    __builtin_amdgcn_s_setprio(1);
#pragma unroll
    for (int i = 0; i < 4; ++i)
#pragma unroll
      for (int j = 0; j < 4; ++j)
        acc[i][j] = __builtin_amdgcn_mfma_f32_16x16x32_bf16(af[i], bfr[j], acc[i][j], 0, 0, 0);
    __builtin_amdgcn_s_setprio(0);
    __builtin_amdgcn_s_barrier();

    // ---- P2: kc0, ms1 ----
#pragma unroll
    for (int i = 0; i < 4; ++i) af[i] = ldb8b(bufA + ((wr * 8 + 4 + i) << 10) + loff);
    if (pf) STG_B(kt + 1, 0);
    __builtin_amdgcn_s_barrier();
    __builtin_amdgcn_s_setprio(1);
#pragma unroll
    for (int i = 0; i < 4; ++i)
#pragma unroll
      for (int j = 0; j < 4; ++j)
        acc[4 + i][j] = __builtin_amdgcn_mfma_f32_16x16x32_bf16(af[i], bfr[j], acc[4 + i][j], 0, 0, 0);
    __builtin_amdgcn_s_setprio(0);
    asm volatile("s_waitcnt vmcnt(4)" ::: "memory");
    __builtin_amdgcn_s_barrier();

    // ---- P3: kc1, ms0 ----
#pragma unroll
    for (int j = 0; j < 4; ++j) bfr[j] = ldb8b(bufB + 16384 + ((wc * 4 + j) << 10) + loff);
#pragma unroll
    for (int i = 0; i < 4; ++i) af[i] = ldb8b(bufA + 16384 + ((wr * 8 + i) << 10) + loff);
    if (pf) STG_A(kt + 1, 1);
    __builtin_amdgcn_s_barrier();
    __builtin_amdgcn_s_setprio(1);
#pragma unroll
    for (int i = 0; i < 4; ++i)
#pragma unroll
      for (int j = 0; j < 4; ++j)
        acc[i][j] = __builtin_amdgcn_mfma_f32_16x16x32_bf16(af[i], bfr[j], acc[i][j], 0, 0, 0);
    __builtin_amdgcn_s_setprio(0);
    __builtin_amdgcn_s_barrier();

    // ---- P4: kc1, ms1 ----
#pragma unroll
    for (int i = 0; i < 4; ++i) af[i] = ldb8b(bufA + 16384 + ((wr * 8 + 4 + i) << 10) + loff);
    if (pf) STG_B(kt + 1, 1);
    __builtin_amdgcn_s_barrier();
    __builtin_amdgcn_s_setprio(1);
#pragma unroll
    for (int i = 0; i < 4; ++i)
#pragma unroll
      for (int j = 0; j < 4; ++j)
        acc[4 + i][j] = __builtin_amdgcn_mfma_f32_16x16x32_bf16(af[i], bfr[j], acc[4 + i][j], 0, 0, 0);
    __builtin_amdgcn_s_setprio(0);
    asm volatile("s_waitcnt vmcnt(4)" ::: "memory");
    __builtin_amdgcn_s_barrier();
  }
#undef STG_A
#undef STG_B

  if (MODE == 1) {
#pragma unroll
    for (int i = 0; i < 8; ++i)
#pragma unroll
      for (int j = 0; j < 4; ++j)
#pragma unroll
        for (int r = 0; r < 4; ++r) {
          int m = m0 + wr * 128 + i * 16 + lg * 4 + r;
          int n = n0 + wc * 64 + j * 16 + l16;
          Cf[(size_t)m * N + n] = acc[i][j][r];
        }
  } else {
    int slice = (n0 >> 7) + (wc >> 1);
#pragma unroll
    for (int i = 0; i < 8; ++i)
#pragma unroll
      for (int j = 0; j < 4; ++j)
#pragma unroll
        for (int r = 0; r < 4; ++r) {
          int m = m0 + wr * 128 + i * 16 + lg * 4 + r;
          int d = ((wc & 1) << 6) + j * 16 + l16;
          int b = m >> 11, s = m & (S_ - 1);
          u16 val = f2b(acc[i][j][r]);
          if (slice < NH_) {
            Qb[(((size_t)b * NH_ + slice) * S_ + s) * HD_ + d] = val;
          } else if (slice < NH_ + NKV_) {
            Kb[(((size_t)b * NKV_ + (slice - NH_)) * S_ + s) * HD_ + d] = val;
          } else {
            Vb[(((size_t)b * NKV_ + (slice - NH_ - NKV_)) * HD_ + d) * S_ + s] = val;
          }
        }
  }
}

__global__ __launch_bounds__(512, 2) void k_gemm_qkv(const u16* __restrict__ A,
                                                     const u16* __restrict__ Bt,
                                                     u16* __restrict__ Qb,
                                                     u16* __restrict__ Kb,
                                                     u16* __restrict__ Vb,
                                                     int M, int N, int Kd) {
  gemm_body<0>(A, Bt, nullptr, Qb, Kb, Vb, M, N, Kd);
}

__global__ __launch_bounds__(512, 2) void k_gemm_out(const u16* __restrict__ A,
                                                     const u16* __restrict__ Bt,
                                                     float* __restrict__ Cf,
                                                     int M, int N, int Kd) {
  gemm_body<1>(A, Bt, Cf, nullptr, nullptr, nullptr, M, N, Kd);
}

// ---------- kernel 4: RoPE ----------
__global__ __launch_bounds__(256) void k_rope(u16* __restrict__ buf, const int* __restrict__ pos,
                                              const float* __restrict__ ct, const float* __restrict__ st,
                                              int H, int rows) {
  int wave = threadIdx.x >> 6, lane = threadIdx.x & 63;
  int row = blockIdx.x * 4 + wave;
  if (row >= rows) return;
  int s = row & (S_ - 1);
  int b = row / (H * S_);
  int p = pos[b * S_ + s];
  size_t base = (size_t)row * HD_;
  float x1 = b2f(buf[base + lane]);
  float x2 = b2f(buf[base + 64 + lane]);
  float c  = ct[(size_t)p * HD_ + lane];
  float sn = st[(size_t)p * HD_ + lane];
  buf[base + lane]      = f2b(x1 * c - x2 * sn);
  buf[base + 64 + lane] = f2b(x2 * c + x1 * sn);
}

// ---------- kernel 5: causal GQA flash attention (unchanged) ----------
__global__ __launch_bounds__(256, 4) void k_attn(const u16* __restrict__ Q,
                                                 const u16* __restrict__ K,
                                                 const u16* __restrict__ Vt,
                                                 u16* __restrict__ Ob) {
  __shared__ __align__(16) char smem[40960];
  const int VS_OFF = 16384, PS_OFF = 32768;

  int bid = blockIdx.x;
  int pid = bid & 15;
  int h   = (bid >> 4) & 31;
  int b   = bid >> 9;
  int kvh = h >> 2;
  int tid = threadIdx.x;
  int wave = tid >> 6, lane = tid & 63;
  int lg = lane >> 4, l16 = lane & 15;
  int lsw = (l16 & 7) << 4;

  const u16* Qp = Q  + (((size_t)b * NH_  + h)   * S_) * HD_;
  const u16* Kp = K  + (((size_t)b * NKV_ + kvh) * S_) * HD_;
  const u16* Vp = Vt + (((size_t)b * NKV_ + kvh) * HD_) * S_;

  for (int pass = 0; pass < 2; ++pass) {
    int qt = pass ? (31 - pid) : pid;
    int q0 = qt * 64 + wave * 16;
    int qg = q0 + l16;

    bf16x8 qf[4];
#pragma unroll
    for (int c = 0; c < 4; ++c)
      qf[c] = ldb8(&Qp[(size_t)qg * HD_ + c * 32 + lg * 8]);

    f32x4 oacc[8] = {};
    float mrun = -1e30f, lrun = 0.f;

    int nt = qt + 1;
    for (int tI = 0; tI < nt; ++tI) {
      int kb = tI * 64;
      __syncthreads();
#pragma unroll
      for (int i = 0; i < 4; ++i) {
        int ci = i * 256 + tid;
        int r = ci >> 4, ch = ci & 15;
        u16x8 v = *(const u16x8*)&Kp[(size_t)(kb + r) * HD_ + ch * 8];
        *(u16x8*)(smem + r * 256 + ((ch * 16) ^ ((r & 7) << 4))) = v;
      }
#pragma unroll
      for (int i = 0; i < 4; ++i) {
        int ci = i * 256 + tid;
        int r = ci >> 3, ch = ci & 7;
        u16x8 v = *(const u16x8*)&Vp[(size_t)r * S_ + kb + ch * 8];
        *(u16x8*)(smem + VS_OFF + r * 128 + ((ch * 16) ^ ((r & 7) << 4))) = v;
      }
      __syncthreads();

      f32x4 sc[4] = {};
#pragma unroll
      for (int c = 0; c < 4; ++c) {
#pragma unroll
        for (int n = 0; n < 4; ++n) {
          bf16x8 kf = ldb8b(smem + (n * 16 + l16) * 256 + ((c * 64 + lg * 16) ^ lsw));
          sc[n] = __builtin_amdgcn_mfma_f32_16x16x32_bf16(kf, qf[c], sc[n], 0, 0, 0);
        }
      }

      bool diag = (tI == qt);
      float mx = -1e30f;
#pragma unroll
      for (int n = 0; n < 4; ++n)
#pragma unroll
        for (int r = 0; r < 4; ++r) {
          float v = sc[n][r];
          int key = kb + n * 16 + lg * 4 + r;
          if (diag && key > qg) v = -1e30f;
          sc[n][r] = v;
          mx = fmaxf(mx, v);
        }
      mx = fmaxf(mx, __shfl_xor(mx, 16));
      mx = fmaxf(mx, __shfl_xor(mx, 32));
      float mnew = fmaxf(mrun, mx * SCALE_);
      float alpha = __expf(mrun - mnew);
      float ps = 0.f;
#pragma unroll
      for (int n = 0; n < 4; ++n) {
        u16x4 pk;
#pragma unroll
        for (int r = 0; r < 4; ++r) {
          float p = __expf(fmaf(sc[n][r], SCALE_, -mnew));
          ps += p;
          pk[r] = f2b(p);
        }
        *(u16x4*)(smem + PS_OFF + wave * 2048 + l16 * 128 + ((n * 32 + lg * 8) ^ lsw)) = pk;
      }
      ps += __shfl_xor(ps, 16);
      ps += __shfl_xor(ps, 32);
      lrun = lrun * alpha + ps;
      mrun = mnew;

      float ar[4];
#pragma unroll
      for (int r = 0; r < 4; ++r) ar[r] = __shfl(alpha, lg * 4 + r);
#pragma unroll
      for (int ns = 0; ns < 8; ++ns)
#pragma unroll
        for (int r = 0; r < 4; ++r) oacc[ns][r] *= ar[r];

#pragma unroll
      for (int ck = 0; ck < 2; ++ck) {
        bf16x8 pa = ldb8b(smem + PS_OFF + wave * 2048 + l16 * 128 + ((ck * 64 + lg * 16) ^ lsw));
#pragma unroll
        for (int ns = 0; ns < 8; ++ns) {
          bf16x8 vf = ldb8b(smem + VS_OFF + (ns * 16 + l16) * 128 + ((ck * 64 + lg * 16) ^ lsw));
          oacc[ns] = __builtin_amdgcn_mfma_f32_16x16x32_bf16(pa, vf, oacc[ns], 0, 0, 0);
        }
      }
    }

    float lr[4];
#pragma unroll
    for (int r = 0; r < 4; ++r) lr[r] = 1.0f / __shfl(lrun, lg * 4 + r);
#pragma unroll
    for (int ns = 0; ns < 8; ++ns)
#pragma unroll
      for (int r = 0; r < 4; ++r) {
        int q = q0 + lg * 4 + r;
        Ob[((size_t)(b * S_) + q) * (NH_ * HD_) + h * HD_ + ns * 16 + l16] =
            f2b(oacc[ns][r] * lr[r]);
      }
  }
}

// ---------- launch ----------
extern "C" void kernel_launch(void* const* d_in, const int* in_sizes, int n_in,
                              void* d_out, int out_size, void* d_ws, size_t ws_size,
                              hipStream_t stream) {
  const float* hs  = (const float*)d_in[0];
  const int*   pos = (const int*)d_in[1];
  const float* ct  = (const float*)d_in[2];
  const float* st  = (const float*)d_in[3];
  const float* Wq  = (const float*)d_in[4];
  const float* Wk  = (const float*)d_in[5];
  const float* Wv  = (const float*)d_in[6];
  const float* Wo  = (const float*)d_in[7];
  float* out = (float*)d_out;

  char* w = (char*)d_ws;
  u16* Xb    = (u16*)(w);                       // [4096][4096]
  u16* WqkvT = (u16*)(w + 33554432ull);         // [6144][4096]
  u16* WoT   = (u16*)(w + 83886080ull);         // [4096][4096]
  u16* Qb    = (u16*)(w + 117440512ull);        // [2][32][2048][128]
  u16* Kb    = (u16*)(w + 150994944ull);        // [2][8][2048][128]
  u16* Vb    = (u16*)(w + 159383552ull);        // [2][8][128][2048]
  u16* Attb  = (u16*)(w + 167772160ull);        // [4096][4096]

  k_convx<<<16384, 256, 0, stream>>>(hs, Xb, 4194304);
  k_convT<<<dim3(64, 64), 256, 0, stream>>>(Wq, WqkvT, 4096, 4096);
  k_convT<<<dim3(64, 16), 256, 0, stream>>>(Wk, WqkvT + (size_t)4096 * 4096, 1024, 4096);
  k_convT<<<dim3(64, 16), 256, 0, stream>>>(Wv, WqkvT + (size_t)5120 * 4096, 1024, 4096);
  k_convT<<<dim3(64, 64), 256, 0, stream>>>(Wo, WoT, 4096, 4096);
  k_gemm_qkv<<<dim3(24, 16), 512, 0, stream>>>(Xb, WqkvT, Qb, Kb, Vb, 4096, NTOT_, 4096);
  k_rope<<<32768, 256, 0, stream>>>(Qb, pos, ct, st, NH_, B_ * NH_ * S_);
  k_rope<<<8192, 256, 0, stream>>>(Kb, pos, ct, st, NKV_, B_ * NKV_ * S_);
  k_attn<<<1024, 256, 0, stream>>>(Qb, Kb, Vb, Attb);
  k_gemm_out<<<dim3(16, 16), 512, 0, stream>>>(Attb, WoT, out, 4096, 4096, 4096);
}